// Round 3
// baseline (61.246 us; speedup 1.0000x reference)
//
#include <hip/hip_runtime.h>
#include <hip/hip_bf16.h>

#define A_N 8
#define C_N 256
#define H_N 80
#define W_N 108
#define P_N (H_N * W_N)      // 8640
#define O_N 7
#define MH 256               // mask H
#define MW 256               // mask W
#define OUT_HW 256

__device__ __forceinline__ float sigmoidf_(float zv) {
    return 1.0f / (1.0f + __expf(-zv));
}

// ---------------------------------------------------------------------------
// Fused kernel: antialias resize of car_masks (inline, per-pixel) + 1x1 conv.
//   z[a,o,p]     = sum_c w[o,c]*x[a,c,p] + wsum[o]*cm[a,p]
//   ssolo[a,o,p] = sigmoid(z + b[o])
// Grid 135 x 256 threads, 2 px/thread (float2): exact cover, zero CU tail.
// ---------------------------------------------------------------------------
__launch_bounds__(256)
__global__ void k_conv(const float* __restrict__ x, const float* __restrict__ masks,
                       const float* __restrict__ w, const float* __restrict__ b,
                       float* __restrict__ z, float* __restrict__ ssolo)
{
    __shared__ float s_wsum[O_N];
    if (threadIdx.x < O_N) {
        const float4* wr = reinterpret_cast<const float4*>(w + threadIdx.x * C_N);
        float s = 0.0f;
        for (int c4 = 0; c4 < C_N / 4; ++c4) {
            float4 v = wr[c4];
            s += v.x + v.y + v.z + v.w;
        }
        s_wsum[threadIdx.x] = s;
    }
    __syncthreads();

    const int t  = blockIdx.x * 256 + threadIdx.x;   // pixel-pair index < 34560
    const int gp = t * 2;
    const int a  = gp / P_N;
    const int p0 = gp - a * P_N;
    const int oy = p0 / W_N;
    const int ox0 = p0 - oy * W_N;                   // pair is same row (W even)

    // ---- inline antialias resize (jax.image.resize bilinear, antialias) ----
    const float ksy = 256.0f / 80.0f;
    const float ksx = 256.0f / 108.0f;
    const float rky = 0.3125f;       // 80/256 exact
    const float rkx = 0.421875f;     // 108/256 exact

    float sfy = ((float)oy + 0.5f) * ksy - 0.5f;
    int iy0 = max(0, (int)ceilf(sfy - ksy));
    int iy1 = min(MH - 1, (int)floorf(sfy + ksy));
    float wys = 0.0f;
    for (int iy = iy0; iy <= iy1; ++iy)
        wys += fmaxf(0.0f, 1.0f - fabsf(sfy - (float)iy) * rky);

    float cmv[2];
    const float* mp = masks + a * (MH * MW);
    #pragma unroll
    for (int q = 0; q < 2; ++q) {
        float sfx = ((float)(ox0 + q) + 0.5f) * ksx - 0.5f;
        int ix0 = max(0, (int)ceilf(sfx - ksx));
        int ix1 = min(MW - 1, (int)floorf(sfx + ksx));
        float wxs = 0.0f;
        for (int ix = ix0; ix <= ix1; ++ix)
            wxs += fmaxf(0.0f, 1.0f - fabsf(sfx - (float)ix) * rkx);
        float acc = 0.0f;
        for (int iy = iy0; iy <= iy1; ++iy) {
            float wyv = fmaxf(0.0f, 1.0f - fabsf(sfy - (float)iy) * rky);
            const float* row = mp + iy * MW;
            float racc = 0.0f;
            for (int ix = ix0; ix <= ix1; ++ix)
                racc += fmaxf(0.0f, 1.0f - fabsf(sfx - (float)ix) * rkx) * row[ix];
            acc += wyv * racc;
        }
        cmv[q] = acc / (wys * wxs);
    }

    // ---- 1x1 conv over 256 channels, 2 px via float2 streaming loads ----
    float acc0[O_N], acc1[O_N];
    #pragma unroll
    for (int o = 0; o < O_N; ++o) { acc0[o] = 0.0f; acc1[o] = 0.0f; }

    const float* xp = x + (size_t)a * C_N * P_N + p0;
    #pragma unroll 8
    for (int c = 0; c < C_N; ++c) {
        float2 v = *reinterpret_cast<const float2*>(xp + (size_t)c * P_N);
        #pragma unroll
        for (int o = 0; o < O_N; ++o) {
            float wv = w[o * C_N + c];
            acc0[o] = fmaf(wv, v.x, acc0[o]);
            acc1[o] = fmaf(wv, v.y, acc1[o]);
        }
    }

    const int zb = (a * O_N) * P_N + p0;
    #pragma unroll
    for (int o = 0; o < O_N; ++o) {
        float z0 = acc0[o] + s_wsum[o] * cmv[0];
        float z1 = acc1[o] + s_wsum[o] * cmv[1];
        float bo = b[o];
        *reinterpret_cast<float2*>(z + zb + o * P_N)     = make_float2(z0, z1);
        *reinterpret_cast<float2*>(ssolo + zb + o * P_N) =
            make_float2(sigmoidf_(z0 + bo), sigmoidf_(z1 + bo));
    }
}

// ---------------------------------------------------------------------------
// Aggregation: per ego i, pixel p: saggr = sigmoid(b + sum_j adj[i,j]!=0 ?
//              zero-padded-bilinear(z[j], rel[i,j] @ [u,v,1]) : 0)
// z planes total 1.9 MB — L2-resident gathers. 135 x 512 exact cover.
// ---------------------------------------------------------------------------
__launch_bounds__(512)
__global__ void k_aggr(const float* __restrict__ z, const float* __restrict__ rel,
                       const int* __restrict__ adj, const float* __restrict__ b,
                       float* __restrict__ saggr)
{
    const int idx = blockIdx.x * 512 + threadIdx.x;   // < 69120 exact
    const int i = idx / P_N, p = idx - i * P_N;
    const int vy = p / W_N, ux = p - vy * W_N;
    const float fu = (float)ux, fv = (float)vy;

    float acc[O_N];
    #pragma unroll
    for (int o = 0; o < O_N; ++o) acc[o] = b[o];

    for (int j = 0; j < A_N; ++j) {
        if (adj[i * A_N + j] == 0) continue;
        const float* M = rel + (i * A_N + j) * 6;
        float sx = M[0] * fu + M[1] * fv + M[2];
        float sy = M[3] * fu + M[4] * fv + M[5];
        if (!(sx > -1.0f && sx < (float)W_N && sy > -1.0f && sy < (float)H_N)) continue;
        float x0f = floorf(sx), y0f = floorf(sy);
        float wx = sx - x0f, wy = sy - y0f;
        int x0 = (int)x0f, y0 = (int)y0f;
        int x1 = x0 + 1,  y1 = y0 + 1;
        float w00 = (1.0f - wy) * (1.0f - wx), w01 = (1.0f - wy) * wx;
        float w10 = wy * (1.0f - wx),          w11 = wy * wx;
        if (x0 < 0)    { w00 = 0.0f; w10 = 0.0f; x0 = 0; }
        if (x1 >= W_N) { w01 = 0.0f; w11 = 0.0f; x1 = W_N - 1; }
        if (y0 < 0)    { w00 = 0.0f; w01 = 0.0f; y0 = 0; }
        if (y1 >= H_N) { w10 = 0.0f; w11 = 0.0f; y1 = H_N - 1; }
        const int i00 = y0 * W_N + x0, i01 = y0 * W_N + x1;
        const int i10 = y1 * W_N + x0, i11 = y1 * W_N + x1;
        const float* zj = z + j * O_N * P_N;
        #pragma unroll
        for (int o = 0; o < O_N; ++o) {
            const float* zp = zj + o * P_N;
            acc[o] += w00 * zp[i00] + w01 * zp[i01] + w10 * zp[i10] + w11 * zp[i11];
        }
    }
    const int ob = i * O_N * P_N + p;
    #pragma unroll
    for (int o = 0; o < O_N; ++o) saggr[ob + o * P_N] = sigmoidf_(acc[o]);
}

// ---------------------------------------------------------------------------
// Upsample: align_corners=True bilinear 80x108 -> 256x256, f32 out.
// 4 px/thread -> float4 stores; 7168 blocks x 256 exact.
// Output layout: [solo(8,7,256,256), aggr(8,7,256,256)] flat f32.
// ---------------------------------------------------------------------------
__launch_bounds__(256)
__global__ void k_upsample(const float* __restrict__ ssolo, const float* __restrict__ saggr,
                           float* __restrict__ out)
{
    const int idx = blockIdx.x * 256 + threadIdx.x;   // quad index
    int k = idx;
    const int oxq = k & 63;   k >>= 6;
    const int oy  = k & 255;  k >>= 8;
    const int o   = k % O_N;  k /= O_N;
    const int a   = k & 7;    k >>= 3;
    const int t   = k;        // 0 = solo, 1 = aggr

    const float* src = (t == 0 ? ssolo : saggr) + (a * O_N + o) * P_N;
    float syf = (float)oy * (79.0f / 255.0f);
    int y0 = (int)syf; y0 = min(y0, H_N - 2);
    float wy = syf - (float)y0;
    const float* r0 = src + y0 * W_N;
    const float* r1 = r0 + W_N;

    float res[4];
    #pragma unroll
    for (int q = 0; q < 4; ++q) {
        int ox = oxq * 4 + q;
        float sxf = (float)ox * (107.0f / 255.0f);
        int x0 = (int)sxf; x0 = min(x0, W_N - 2);
        float wx = sxf - (float)x0;
        float c0 = r0[x0]     * (1.0f - wy) + r1[x0]     * wy;
        float c1 = r0[x0 + 1] * (1.0f - wy) + r1[x0 + 1] * wy;
        res[q] = c0 * (1.0f - wx) + c1 * wx;
    }
    *reinterpret_cast<float4*>(out + (size_t)idx * 4) =
        make_float4(res[0], res[1], res[2], res[3]);
}

// ---------------------------------------------------------------------------
extern "C" void kernel_launch(void* const* d_in, const int* in_sizes, int n_in,
                              void* d_out, int out_size, void* d_ws, size_t ws_size,
                              hipStream_t stream)
{
    (void)in_sizes; (void)n_in; (void)out_size; (void)ws_size;
    const float* x    = (const float*)d_in[0];
    const float* rel  = (const float*)d_in[1];
    const int*   adj  = (const int*)d_in[2];
    const float* cmsk = (const float*)d_in[3];
    const float* wcls = (const float*)d_in[4];
    const float* bcls = (const float*)d_in[5];
    float* out = (float*)d_out;   // reference output dtype is float32

    float* ws    = (float*)d_ws;
    float* z     = ws;                          // 8*7*8640 = 483,840 f32
    float* ssolo = z     + A_N * O_N * P_N;     // 483,840 f32
    float* saggr = ssolo + A_N * O_N * P_N;     // 483,840 f32  (~5.8 MB total)

    k_conv<<<135, 256, 0, stream>>>(x, cmsk, wcls, bcls, z, ssolo);
    k_aggr<<<135, 512, 0, stream>>>(z, rel, adj, bcls, saggr);
    k_upsample<<<7168, 256, 0, stream>>>(ssolo, saggr, out);
}

// Round 4
// 50.959 us; speedup vs baseline: 1.2019x; 1.2019x over previous
//
#include <hip/hip_runtime.h>
#include <hip/hip_bf16.h>

#define A_N 8
#define C_N 256
#define H_N 80
#define W_N 108
#define P_N (H_N * W_N)      // 8640
#define O_N 7
#define MH 256               // mask H
#define MW 256               // mask W
#define OUT_HW 256

#define CG   8               // channel groups per block
#define CPB  32              // channels per group (C_N/CG)
#define PXB  64              // pixels per block
#define BPA  135             // blocks per agent (P_N/PXB)

__device__ __forceinline__ float sigmoidf_(float zv) {
    return 1.0f / (1.0f + __expf(-zv));
}

// ---------------------------------------------------------------------------
// Fused resize+conv, channel-split for occupancy.
// Grid: 8*135 = 1080 blocks x 256 thr. Block = 64 px (32 float2 pairs) x 8
// channel-groups of 32 ch. LDS partial-sum reduce (deterministic).
//   z[a,o,p]     = sum_c w[o,c]*x[a,c,p] + wsum[o]*cm[a,p]
//   ssolo[a,o,p] = sigmoid(z + b[o])
// ---------------------------------------------------------------------------
__launch_bounds__(256)
__global__ void k_conv(const float* __restrict__ x, const float* __restrict__ masks,
                       const float* __restrict__ w, const float* __restrict__ b,
                       float* __restrict__ z, float* __restrict__ ssolo)
{
    __shared__ float s_w8[C_N][8];              // w transposed, padded to 8 -> b128 reads
    __shared__ float s_acc[CG][PXB / 2][2 * O_N];
    __shared__ float s_cm[PXB];
    __shared__ float s_wsum[O_N];

    const int tid = threadIdx.x;

    // stage w into LDS as s_w8[c][o] (8 entries per thread, coalesced LDS writes)
    #pragma unroll
    for (int k = 0; k < 8; ++k) {
        int idx = k * 256 + tid;                // = c*8 + o
        int c = idx >> 3, o = idx & 7;
        s_w8[c][o] = (o < O_N) ? w[o * C_N + c] : 0.0f;
    }
    if (tid < O_N) {
        const float4* wr = reinterpret_cast<const float4*>(w + tid * C_N);
        float s = 0.0f;
        #pragma unroll 4
        for (int c4 = 0; c4 < C_N / 4; ++c4) { float4 v = wr[c4]; s += v.x + v.y + v.z + v.w; }
        s_wsum[tid] = s;
    }
    __syncthreads();

    const int pr = tid & 31;                    // pixel-pair within block
    const int cg = tid >> 5;                    // channel group
    const int a  = blockIdx.x / BPA;
    const int p0base = (blockIdx.x - a * BPA) * PXB;
    const int p0 = p0base + pr * 2;

    float a0[O_N], a1[O_N];
    #pragma unroll
    for (int o = 0; o < O_N; ++o) { a0[o] = 0.0f; a1[o] = 0.0f; }

    const float* xp = x + (size_t)(a * C_N + cg * CPB) * P_N + p0;
    #pragma unroll 8
    for (int cc = 0; cc < CPB; ++cc) {
        float2 v = *reinterpret_cast<const float2*>(xp + (size_t)cc * P_N);
        const int c = cg * CPB + cc;
        float4 wA = *reinterpret_cast<const float4*>(&s_w8[c][0]);
        float4 wB = *reinterpret_cast<const float4*>(&s_w8[c][4]);
        a0[0] = fmaf(wA.x, v.x, a0[0]); a1[0] = fmaf(wA.x, v.y, a1[0]);
        a0[1] = fmaf(wA.y, v.x, a0[1]); a1[1] = fmaf(wA.y, v.y, a1[1]);
        a0[2] = fmaf(wA.z, v.x, a0[2]); a1[2] = fmaf(wA.z, v.y, a1[2]);
        a0[3] = fmaf(wA.w, v.x, a0[3]); a1[3] = fmaf(wA.w, v.y, a1[3]);
        a0[4] = fmaf(wB.x, v.x, a0[4]); a1[4] = fmaf(wB.x, v.y, a1[4]);
        a0[5] = fmaf(wB.y, v.x, a0[5]); a1[5] = fmaf(wB.y, v.y, a1[5]);
        a0[6] = fmaf(wB.z, v.x, a0[6]); a1[6] = fmaf(wB.z, v.y, a1[6]);
    }

    // wave 0: inline antialias resize (jax.image.resize bilinear, antialias=True)
    if (tid < PXB) {
        const int pp = p0base + tid;
        const int oy = pp / W_N, ox = pp - oy * W_N;
        const float ksy = 256.0f / 80.0f;
        const float ksx = 256.0f / 108.0f;
        const float rky = 0.3125f;              // 80/256 exact
        const float rkx = 0.421875f;            // 108/256 exact

        float sfy = ((float)oy + 0.5f) * ksy - 0.5f;
        float sfx = ((float)ox + 0.5f) * ksx - 0.5f;
        int iy0 = max(0, (int)ceilf(sfy - ksy));
        int iy1 = min(MH - 1, (int)floorf(sfy + ksy));
        int ix0 = max(0, (int)ceilf(sfx - ksx));
        int ix1 = min(MW - 1, (int)floorf(sfx + ksx));

        float wys = 0.0f, wxs = 0.0f;
        for (int iy = iy0; iy <= iy1; ++iy)
            wys += fmaxf(0.0f, 1.0f - fabsf(sfy - (float)iy) * rky);
        for (int ix = ix0; ix <= ix1; ++ix)
            wxs += fmaxf(0.0f, 1.0f - fabsf(sfx - (float)ix) * rkx);

        const float* mp = masks + a * (MH * MW);
        float acc = 0.0f;
        for (int iy = iy0; iy <= iy1; ++iy) {
            float wyv = fmaxf(0.0f, 1.0f - fabsf(sfy - (float)iy) * rky);
            const float* row = mp + iy * MW;
            float racc = 0.0f;
            for (int ix = ix0; ix <= ix1; ++ix)
                racc += fmaxf(0.0f, 1.0f - fabsf(sfx - (float)ix) * rkx) * row[ix];
            acc += wyv * racc;
        }
        s_cm[tid] = acc / (wys * wxs);
    }

    #pragma unroll
    for (int o = 0; o < O_N; ++o) {
        s_acc[cg][pr][2 * o]     = a0[o];
        s_acc[cg][pr][2 * o + 1] = a1[o];
    }
    __syncthreads();

    // reduce: 224 threads = 7 outputs x 32 pairs
    if (tid < O_N * 32) {
        const int o   = tid >> 5;
        const int pr2 = tid & 31;
        float s0 = 0.0f, s1 = 0.0f;
        #pragma unroll
        for (int g = 0; g < CG; ++g) {
            s0 += s_acc[g][pr2][2 * o];
            s1 += s_acc[g][pr2][2 * o + 1];
        }
        const float wsum = s_wsum[o];
        const float z0 = s0 + wsum * s_cm[pr2 * 2];
        const float z1 = s1 + wsum * s_cm[pr2 * 2 + 1];
        const float bo = b[o];
        const size_t ob = (size_t)(a * O_N + o) * P_N + p0base + pr2 * 2;
        *reinterpret_cast<float2*>(z + ob)     = make_float2(z0, z1);
        *reinterpret_cast<float2*>(ssolo + ob) =
            make_float2(sigmoidf_(z0 + bo), sigmoidf_(z1 + bo));
    }
}

// ---------------------------------------------------------------------------
// Aggregation: per ego i, pixel p: saggr = sigmoid(b + sum_j adj[i,j]!=0 ?
//              zero-padded-bilinear(z[j], rel[i,j] @ [u,v,1]) : 0)
// z planes total 1.9 MB — L2-resident gathers. 135 x 512 exact cover.
// ---------------------------------------------------------------------------
__launch_bounds__(512)
__global__ void k_aggr(const float* __restrict__ z, const float* __restrict__ rel,
                       const int* __restrict__ adj, const float* __restrict__ b,
                       float* __restrict__ saggr)
{
    const int idx = blockIdx.x * 512 + threadIdx.x;   // < 69120 exact
    const int i = idx / P_N, p = idx - i * P_N;
    const int vy = p / W_N, ux = p - vy * W_N;
    const float fu = (float)ux, fv = (float)vy;

    float acc[O_N];
    #pragma unroll
    for (int o = 0; o < O_N; ++o) acc[o] = b[o];

    for (int j = 0; j < A_N; ++j) {
        if (adj[i * A_N + j] == 0) continue;
        const float* M = rel + (i * A_N + j) * 6;
        float sx = M[0] * fu + M[1] * fv + M[2];
        float sy = M[3] * fu + M[4] * fv + M[5];
        if (!(sx > -1.0f && sx < (float)W_N && sy > -1.0f && sy < (float)H_N)) continue;
        float x0f = floorf(sx), y0f = floorf(sy);
        float wx = sx - x0f, wy = sy - y0f;
        int x0 = (int)x0f, y0 = (int)y0f;
        int x1 = x0 + 1,  y1 = y0 + 1;
        float w00 = (1.0f - wy) * (1.0f - wx), w01 = (1.0f - wy) * wx;
        float w10 = wy * (1.0f - wx),          w11 = wy * wx;
        if (x0 < 0)    { w00 = 0.0f; w10 = 0.0f; x0 = 0; }
        if (x1 >= W_N) { w01 = 0.0f; w11 = 0.0f; x1 = W_N - 1; }
        if (y0 < 0)    { w00 = 0.0f; w01 = 0.0f; y0 = 0; }
        if (y1 >= H_N) { w10 = 0.0f; w11 = 0.0f; y1 = H_N - 1; }
        const int i00 = y0 * W_N + x0, i01 = y0 * W_N + x1;
        const int i10 = y1 * W_N + x0, i11 = y1 * W_N + x1;
        const float* zj = z + j * O_N * P_N;
        #pragma unroll
        for (int o = 0; o < O_N; ++o) {
            const float* zp = zj + o * P_N;
            acc[o] += w00 * zp[i00] + w01 * zp[i01] + w10 * zp[i10] + w11 * zp[i11];
        }
    }
    const int ob = i * O_N * P_N + p;
    #pragma unroll
    for (int o = 0; o < O_N; ++o) saggr[ob + o * P_N] = sigmoidf_(acc[o]);
}

// ---------------------------------------------------------------------------
// Upsample: align_corners=True bilinear 80x108 -> 256x256, f32 out.
// 4 px/thread -> float4 stores; 7168 blocks x 256 exact.
// Output layout: [solo(8,7,256,256), aggr(8,7,256,256)] flat f32.
// ---------------------------------------------------------------------------
__launch_bounds__(256)
__global__ void k_upsample(const float* __restrict__ ssolo, const float* __restrict__ saggr,
                           float* __restrict__ out)
{
    const int idx = blockIdx.x * 256 + threadIdx.x;   // quad index
    int k = idx;
    const int oxq = k & 63;   k >>= 6;
    const int oy  = k & 255;  k >>= 8;
    const int o   = k % O_N;  k /= O_N;
    const int a   = k & 7;    k >>= 3;
    const int t   = k;        // 0 = solo, 1 = aggr

    const float* src = (t == 0 ? ssolo : saggr) + (a * O_N + o) * P_N;
    float syf = (float)oy * (79.0f / 255.0f);
    int y0 = (int)syf; y0 = min(y0, H_N - 2);
    float wy = syf - (float)y0;
    const float* r0 = src + y0 * W_N;
    const float* r1 = r0 + W_N;

    float res[4];
    #pragma unroll
    for (int q = 0; q < 4; ++q) {
        int ox = oxq * 4 + q;
        float sxf = (float)ox * (107.0f / 255.0f);
        int x0 = (int)sxf; x0 = min(x0, W_N - 2);
        float wx = sxf - (float)x0;
        float c0 = r0[x0]     * (1.0f - wy) + r1[x0]     * wy;
        float c1 = r0[x0 + 1] * (1.0f - wy) + r1[x0 + 1] * wy;
        res[q] = c0 * (1.0f - wx) + c1 * wx;
    }
    *reinterpret_cast<float4*>(out + (size_t)idx * 4) =
        make_float4(res[0], res[1], res[2], res[3]);
}

// ---------------------------------------------------------------------------
extern "C" void kernel_launch(void* const* d_in, const int* in_sizes, int n_in,
                              void* d_out, int out_size, void* d_ws, size_t ws_size,
                              hipStream_t stream)
{
    (void)in_sizes; (void)n_in; (void)out_size; (void)ws_size;
    const float* x    = (const float*)d_in[0];
    const float* rel  = (const float*)d_in[1];
    const int*   adj  = (const int*)d_in[2];
    const float* cmsk = (const float*)d_in[3];
    const float* wcls = (const float*)d_in[4];
    const float* bcls = (const float*)d_in[5];
    float* out = (float*)d_out;   // reference output dtype is float32

    float* ws    = (float*)d_ws;
    float* z     = ws;                          // 8*7*8640 = 483,840 f32
    float* ssolo = z     + A_N * O_N * P_N;     // 483,840 f32
    float* saggr = ssolo + A_N * O_N * P_N;     // 483,840 f32  (~5.8 MB total)

    k_conv<<<A_N * BPA, 256, 0, stream>>>(x, cmsk, wcls, bcls, z, ssolo);
    k_aggr<<<135, 512, 0, stream>>>(z, rel, adj, bcls, saggr);
    k_upsample<<<7168, 256, 0, stream>>>(ssolo, saggr, out);
}